// Round 7
// baseline (841.582 us; speedup 1.0000x reference)
//
#include <hip/hip_runtime.h>
#include <hip/hip_bf16.h>

#define B_   4
#define T_   16384
#define CH_  128
#define TCH_ 256
#define NL_  10
#define TT_  64
#define SHW_ 196          // shH row stride in dwords (384 bf16 + 8 pad)
#define HSZ_ (B_ * T_ * CH_)   // one h buffer, in bf16 elements (16 MB)
#define NBLK_ 512

typedef __attribute__((ext_vector_type(8))) short short8;
typedef __attribute__((ext_vector_type(4))) float f32x4;

#define MFMA16(a, b, c) __builtin_amdgcn_mfma_f32_16x16x32_bf16(a, b, c, 0, 0, 0)

__device__ __forceinline__ unsigned short f2bf(float f) {
  unsigned u = __float_as_uint(f);
  return (unsigned short)((u + 0x7FFFu + ((u >> 16) & 1u)) >> 16);
}
__device__ __forceinline__ float bf2f(unsigned s) {
  return __uint_as_float((s & 0xFFFFu) << 16);
}
__device__ __forceinline__ float fast_tanh(float x) {
  float e = __expf(2.0f * fabsf(x));  // inf-safe: e=inf -> t=1
  float t = 1.0f - 2.0f / (e + 1.0f);
  return copysignf(t, x);
}
__device__ __forceinline__ float fast_sig(float x) {
  return 1.0f / (1.0f + __expf(-x));
}

// ---------------------------------------------------------------------------
// Prep: pack weights (bf16) into per-wave MFMA A-fragment order (unchanged
// layout from rounds 2-6).
// ---------------------------------------------------------------------------
__global__ __launch_bounds__(256) void pack_w(
    const float* __restrict__ conv_w, const float* __restrict__ w1x1,
    unsigned short* __restrict__ wpackA, unsigned short* __restrict__ wpack1) {
  const int NA = NL_ * 4 * 4 * 12 * 64 * 8;  // 983040
  int idx = blockIdx.x * 256 + threadIdx.x;
  if (idx < NA) {
    int j = idx & 7;
    int t1 = idx >> 3;
    int l = t1 & 63;
    int t2 = t1 >> 6;
    int ks = t2 % 12;
    int t3 = t2 / 12;
    int f = t3 & 3;
    int t4 = t3 >> 2;
    int w = t4 & 3;
    int li = t4 >> 2;
    int o = 32 * w + 16 * (f & 1) + 128 * (f >> 1) + (l & 15);
    int ck = 32 * ks + 8 * (l >> 4) + j;
    int c = ck & 127, k = ck >> 7;
    wpackA[idx] = f2bf(conv_w[((li * TCH_ + o) * CH_ + c) * 3 + k]);
  } else {
    int i2 = idx - NA;
    if (i2 < NL_ * 4 * 2 * 4 * 64 * 8) {
      int j = i2 & 7;
      int t1 = i2 >> 3;
      int l = t1 & 63;
      int t2 = t1 >> 6;
      int ks = t2 & 3;
      int t3 = t2 >> 2;
      int p = t3 & 1;
      int t4 = t3 >> 1;
      int w = t4 & 3;
      int li = t4 >> 2;
      int o = 32 * w + 16 * p + (l & 15);
      int c = 32 * ks + 8 * (l >> 4) + j;
      wpack1[i2] = f2bf(w1x1[(li * CH_ + o) * CH_ + c]);
    }
  }
}

// ---------------------------------------------------------------------------
// Rechannel into bf16 [b][t][c]: hb[b][t][c] = bf16(w_re[c] * x[b][t])
// ---------------------------------------------------------------------------
__global__ __launch_bounds__(256) void rechannel_k(
    const float* __restrict__ x, const float* __restrict__ w_re,
    unsigned short* __restrict__ hb) {
  int flat = blockIdx.x * 256 + threadIdx.x;  // B*T*16 chunks of 8 ch
  int cid = flat & 15;
  int t = (flat >> 4) & (T_ - 1);
  int b = flat >> 18;
  float xv = x[b * T_ + t];
  const float* wr = w_re + cid * 8;
  union { short8 s; unsigned short u[8]; } o;
#pragma unroll
  for (int j = 0; j < 8; ++j) o.u[j] = f2bf(wr[j] * xv);
  *(short8*)(hb + (size_t)(b * T_ + t) * CH_ + cid * 8) = o.s;
}

// ---------------------------------------------------------------------------
// out_init: out[b][t] = b_head + sum_c w_head[c]*head_init[b][c][t]
// ---------------------------------------------------------------------------
__global__ __launch_bounds__(256) void out_init_k(
    const float* __restrict__ head_init, const float* __restrict__ w_head,
    const float* __restrict__ b_head, float* __restrict__ out) {
  int idx = blockIdx.x * 256 + threadIdx.x;  // over B*T
  int b = idx / T_;
  int t = idx - b * T_;
  float acc = b_head[0];
#pragma unroll 8
  for (int c = 0; c < CH_; ++c)
    acc += w_head[c] * head_init[(b * CH_ + c) * T_ + t];
  out[idx] = acc;
}

// ---------------------------------------------------------------------------
// One layer-tile (round-6 verified body) + flag wait/publish.
// g = b*256 + n identifies the (batch, t-tile). outAcc accumulates the head
// contribution for this tile in registers.
// ---------------------------------------------------------------------------
__device__ __forceinline__ void layer_tile(
    int li, int d, int g,
    const unsigned short* __restrict__ hin,
    unsigned short* __restrict__ hout,
    float* __restrict__ hof,
    const float* __restrict__ cin,
    const unsigned short* __restrict__ wA,
    const unsigned short* __restrict__ w1p,
    const float* __restrict__ bconv, const float* __restrict__ wmix,
    const float* __restrict__ b1, const float* __restrict__ w_head,
    int* __restrict__ flags, float& outAcc,
    unsigned* shH, float* shR, int tid) {
  const int b = g >> 8;
  const int n = g & 255;
  const int t0 = n * TT_;

  // ---- wait for the producer cone of layer li-1 ----
  if (li > 0) {
    int nb = (2 * d + 63) >> 6;
    if (nb > n) nb = n;
    if (tid <= nb) {
      int* fp = flags + (li - 1) * 1024 + (g - tid);
      while (__hip_atomic_load(fp, __ATOMIC_ACQUIRE,
                               __HIP_MEMORY_SCOPE_AGENT) == 0)
        __builtin_amdgcn_s_sleep(2);
    }
  }
  __syncthreads();  // deps ready; also protects shH reuse across items

  // ---- stage H tiles (bf16, fully coalesced 16B chunks) ----
#pragma unroll
  for (int it = 0; it < 12; ++it) {
    int flat = it * 256 + tid;
    int cid = flat & 15;           // 16B chunk within row (8 channels)
    int tt = (flat >> 4) & 63;
    int k = flat >> 10;            // 0..2
    int t = t0 + tt - (2 - k) * d;
    uint4 v = make_uint4(0u, 0u, 0u, 0u);
    if (t >= 0)
      v = *(const uint4*)(hin + ((size_t)(b * T_ + t) * CH_ + cid * 8));
    *(uint4*)(shH + tt * SHW_ + k * 64 + cid * 4) = v;
  }
  __syncthreads();

  const int wave = __builtin_amdgcn_readfirstlane(tid >> 6);
  const int lane = tid & 63;
  const int r = lane & 15;
  const int gg = lane >> 4;

  // ---- conv GEMM: z[256x64] = W[256x384] * H[384x64], 12 K-steps ----
  f32x4 accL[2][4], accH[2][4];
#pragma unroll
  for (int p = 0; p < 2; ++p)
#pragma unroll
    for (int q = 0; q < 4; ++q) {
      accL[p][q] = (f32x4){0.f, 0.f, 0.f, 0.f};
      accH[p][q] = (f32x4){0.f, 0.f, 0.f, 0.f};
    }

  const short8* wAv = (const short8*)wA;
#pragma unroll
  for (int ks = 0; ks < 12; ++ks) {
    short8 bf[4];
#pragma unroll
    for (int q = 0; q < 4; ++q)
      bf[q] = *(const short8*)(shH + (16 * q + r) * SHW_ + 16 * ks + 4 * gg);
    short8 a0 = wAv[((wave * 4 + 0) * 12 + ks) * 64 + lane];
    short8 a1 = wAv[((wave * 4 + 1) * 12 + ks) * 64 + lane];
    short8 a2 = wAv[((wave * 4 + 2) * 12 + ks) * 64 + lane];
    short8 a3 = wAv[((wave * 4 + 3) * 12 + ks) * 64 + lane];
#pragma unroll
    for (int q = 0; q < 4; ++q) {
      accL[0][q] = MFMA16(a0, bf[q], accL[0][q]);
      accL[1][q] = MFMA16(a1, bf[q], accL[1][q]);
      accH[0][q] = MFMA16(a2, bf[q], accH[0][q]);
      accH[1][q] = MFMA16(a3, bf[q], accH[1][q]);
    }
  }
  __syncthreads();  // tap-0 slab now dead -> post may overwrite it

  // ---- gating + in-register head partials; post -> tap-0 alias ----
  float cq[4];
#pragma unroll
  for (int q = 0; q < 4; ++q) cq[q] = cin[b * T_ + t0 + 16 * q + r];

  float hs[4] = {0.f, 0.f, 0.f, 0.f};
#pragma unroll
  for (int p = 0; p < 2; ++p) {
    float bcL[4], bcH[4], wmL[4], wmH[4], whv[4];
#pragma unroll
    for (int j = 0; j < 4; ++j) {
      int o = 32 * wave + 16 * p + 4 * gg + j;
      bcL[j] = bconv[o];
      bcH[j] = bconv[o + CH_];
      wmL[j] = wmix[o];
      wmH[j] = wmix[o + CH_];
      whv[j] = w_head[o];
    }
#pragma unroll
    for (int q = 0; q < 4; ++q) {
      float pv[4];
#pragma unroll
      for (int j = 0; j < 4; ++j) {
        float zl = accL[p][q][j] + bcL[j] + wmL[j] * cq[q];
        float zh = accH[p][q][j] + bcH[j] + wmH[j] * cq[q];
        pv[j] = fast_tanh(zl) * fast_sig(zh);
        hs[q] += whv[j] * pv[j];
      }
      uint2 pk;
      pk.x = (unsigned)f2bf(pv[0]) | ((unsigned)f2bf(pv[1]) << 16);
      pk.y = (unsigned)f2bf(pv[2]) | ((unsigned)f2bf(pv[3]) << 16);
      *(uint2*)(shH + (16 * q + r) * SHW_ + 16 * wave + 8 * p + 2 * gg) = pk;
    }
  }
  __syncthreads();

  // ---- 1x1 GEMM: delta[128x64] = W1 * post ----
  f32x4 acc2[2][4];
#pragma unroll
  for (int p = 0; p < 2; ++p)
#pragma unroll
    for (int q = 0; q < 4; ++q) acc2[p][q] = (f32x4){0.f, 0.f, 0.f, 0.f};

  const short8* w1v = (const short8*)w1p;
#pragma unroll
  for (int ks = 0; ks < 4; ++ks) {
    short8 bp[4];
#pragma unroll
    for (int q = 0; q < 4; ++q)
      bp[q] = *(const short8*)(shH + (16 * q + r) * SHW_ + 16 * ks + 4 * gg);
    short8 a0 = w1v[((wave * 2 + 0) * 4 + ks) * 64 + lane];
    short8 a1 = w1v[((wave * 2 + 1) * 4 + ks) * 64 + lane];
#pragma unroll
    for (int q = 0; q < 4; ++q) {
      acc2[0][q] = MFMA16(a0, bp[q], acc2[0][q]);
      acc2[1][q] = MFMA16(a1, bp[q], acc2[1][q]);
    }
  }

  // ---- residual: res = hin(center tap) + b1 + delta ----
  float res[2][4][4];
  const int o0b = 32 * wave + 4 * gg;
#pragma unroll
  for (int p = 0; p < 2; ++p) {
    const int o0 = o0b + 16 * p;
    float b1v[4];
#pragma unroll
    for (int j = 0; j < 4; ++j) b1v[j] = b1[o0 + j];
#pragma unroll
    for (int q = 0; q < 4; ++q) {
      uint2 hv = *(const uint2*)(shH + (16 * q + r) * SHW_ + 128 + (o0 >> 1));
      res[p][q][0] = bf2f(hv.x) + b1v[0] + acc2[p][q][0];
      res[p][q][1] = bf2f(hv.x >> 16) + b1v[1] + acc2[p][q][1];
      res[p][q][2] = bf2f(hv.y) + b1v[2] + acc2[p][q][2];
      res[p][q][3] = bf2f(hv.y >> 16) + b1v[3] + acc2[p][q][3];
    }
  }

  // ---- head partial reduce -> register accumulator ----
#pragma unroll
  for (int q = 0; q < 4; ++q) {
    hs[q] += __shfl_xor(hs[q], 16);
    hs[q] += __shfl_xor(hs[q], 32);
  }
  if (gg == 0) {
#pragma unroll
    for (int q = 0; q < 4; ++q) shR[(wave * 4 + q) * 16 + r] = hs[q];
  }
  __syncthreads();

  if (tid < 64) {
    int q = tid >> 4, rr = tid & 15;
    outAcc += shR[(0 * 4 + q) * 16 + rr] + shR[(1 * 4 + q) * 16 + rr] +
              shR[(2 * 4 + q) * 16 + rr] + shR[(3 * 4 + q) * 16 + rr];
  }

  if (li < NL_ - 1) {
    // stage hout tile (bf16) into shH dwords 0..63, then coalesced copy
#pragma unroll
    for (int p = 0; p < 2; ++p) {
      const int o0 = o0b + 16 * p;
#pragma unroll
      for (int q = 0; q < 4; ++q) {
        uint2 pk;
        pk.x = (unsigned)f2bf(res[p][q][0]) | ((unsigned)f2bf(res[p][q][1]) << 16);
        pk.y = (unsigned)f2bf(res[p][q][2]) | ((unsigned)f2bf(res[p][q][3]) << 16);
        *(uint2*)(shH + (16 * q + r) * SHW_ + (o0 >> 1)) = pk;
      }
    }
    __syncthreads();
#pragma unroll
    for (int it = 0; it < 4; ++it) {
      int flat = it * 256 + tid;
      int cid = flat & 15;
      int tt = flat >> 4;
      *(uint4*)(hout + ((size_t)(b * T_ + t0 + tt) * CH_ + cid * 8)) =
          *(const uint4*)(shH + tt * SHW_ + cid * 4);
    }
    __syncthreads();  // all stores issued (vmcnt drained per-thread)
    if (tid == 0)
      __hip_atomic_store(flags + li * 1024 + g, 1, __ATOMIC_RELEASE,
                         __HIP_MEMORY_SCOPE_AGENT);
  } else {
    // final layer: fp32 [b][c][t] into d_out (no consumer, no flag)
#pragma unroll
    for (int p = 0; p < 2; ++p) {
      const int o0 = o0b + 16 * p;
#pragma unroll
      for (int q = 0; q < 4; ++q) {
#pragma unroll
        for (int j = 0; j < 4; ++j)
          hof[(size_t)(b * CH_ + o0 + j) * T_ + t0 + 16 * q + r] = res[p][q][j];
      }
    }
  }
}

// ---------------------------------------------------------------------------
// Persistent stack kernel: 512 blocks (all co-resident at 3 blocks/CU),
// 2 tiles per block per layer, flag-pipelined across layers (no grid drain).
// ---------------------------------------------------------------------------
__global__ __launch_bounds__(256, 3) void stack_k(
    unsigned short* __restrict__ hbase,   // 11 h buffers, 16MB each
    float* __restrict__ hof,
    const float* __restrict__ cin, float* __restrict__ out,
    const unsigned short* __restrict__ wpackA,
    const unsigned short* __restrict__ wpack1,
    const float* __restrict__ conv_b, const float* __restrict__ mix_w,
    const float* __restrict__ b1x1, const float* __restrict__ w_head,
    int* __restrict__ flags) {
  __shared__ unsigned shH[TT_ * SHW_];  // 50176 B
  __shared__ float shR[4 * 4 * 16];     // 1 KB

  const int tid = threadIdx.x;
  const int g0 = blockIdx.x;            // b in {0,1}
  const int g1 = blockIdx.x + NBLK_;    // b in {2,3}

  float outAcc0 = 0.f, outAcc1 = 0.f;
  if (tid < 64) {
    int q = tid >> 4, rr = tid & 15;
    outAcc0 = out[(g0 >> 8) * T_ + (g0 & 255) * TT_ + 16 * q + rr];
    outAcc1 = out[(g1 >> 8) * T_ + (g1 & 255) * TT_ + 16 * q + rr];
  }

#pragma unroll 1
  for (int li = 0; li < NL_; ++li) {
    const int d = 1 << li;
    const unsigned short* hin = hbase + (size_t)li * HSZ_;
    unsigned short* hout = hbase + (size_t)(li + 1) * HSZ_;
    const unsigned short* wA  = wpackA + li * (4 * 4 * 12 * 64 * 8);
    const unsigned short* w1p = wpack1 + li * (4 * 2 * 4 * 64 * 8);
    const float* bconv = conv_b + li * TCH_;
    const float* wmix  = mix_w + li * TCH_;
    const float* b1    = b1x1 + li * CH_;

    layer_tile(li, d, g0, hin, hout, hof, cin, wA, w1p, bconv, wmix, b1,
               w_head, flags, outAcc0, shH, shR, tid);
    layer_tile(li, d, g1, hin, hout, hof, cin, wA, w1p, bconv, wmix, b1,
               w_head, flags, outAcc1, shH, shR, tid);
  }

  if (tid < 64) {
    int q = tid >> 4, rr = tid & 15;
    out[(g0 >> 8) * T_ + (g0 & 255) * TT_ + 16 * q + rr] = outAcc0;
    out[(g1 >> 8) * T_ + (g1 & 255) * TT_ + 16 * q + rr] = outAcc1;
  }
}

extern "C" void kernel_launch(void* const* d_in, const int* in_sizes, int n_in,
                              void* d_out, int out_size, void* d_ws, size_t ws_size,
                              hipStream_t stream) {
  const float* x         = (const float*)d_in[0];
  const float* c         = (const float*)d_in[1];
  const float* head_init = (const float*)d_in[2];
  const float* w_re      = (const float*)d_in[3];
  const float* conv_w    = (const float*)d_in[4];
  const float* conv_b    = (const float*)d_in[5];
  const float* mix_w     = (const float*)d_in[6];
  const float* w1x1      = (const float*)d_in[7];
  const float* b1x1      = (const float*)d_in[8];
  const float* w_head    = (const float*)d_in[9];
  const float* b_head    = (const float*)d_in[10];

  float* out = (float*)d_out;          // [B*T]
  float* hof = out + B_ * T_;          // fp32 h region of d_out

  unsigned short* hbase  = (unsigned short*)d_ws;          // 11 x 16MB
  unsigned short* wpackA = hbase + (size_t)11 * HSZ_;
  unsigned short* wpack1 = wpackA + NL_ * 4 * 4 * 12 * 64 * 8;
  int* flags = (int*)(wpack1 + NL_ * 4 * 2 * 4 * 64 * 8);  // 9*1024 ints

  hipMemsetAsync(flags, 0, 9 * 1024 * sizeof(int), stream);

  const int n_pack = NL_ * 4 * 4 * 12 * 64 * 8 + NL_ * 4 * 2 * 4 * 64 * 8;
  pack_w<<<(n_pack + 255) / 256, 256, 0, stream>>>(conv_w, w1x1, wpackA, wpack1);

  rechannel_k<<<(B_ * T_ * 16) / 256, 256, 0, stream>>>(x, w_re, hbase);
  out_init_k<<<(B_ * T_) / 256, 256, 0, stream>>>(head_init, w_head, b_head, out);

  stack_k<<<NBLK_, 256, 0, stream>>>(hbase, hof, c, out, wpackA, wpack1,
                                     conv_b, mix_w, b1x1, w_head,
                                     (int*)flags);
}

// Round 8
// 326.797 us; speedup vs baseline: 2.5752x; 2.5752x over previous
//
#include <hip/hip_runtime.h>
#include <hip/hip_bf16.h>

#define B_   4
#define T_   16384
#define CH_  128
#define TCH_ 256
#define NL_  10
#define TT_  64
#define SHW_ 196          // shH row stride in dwords (384 bf16 + 8 pad)

typedef __attribute__((ext_vector_type(8))) short short8;
typedef __attribute__((ext_vector_type(4))) float f32x4;

#define MFMA16(a, b, c) __builtin_amdgcn_mfma_f32_16x16x32_bf16(a, b, c, 0, 0, 0)

__device__ __forceinline__ unsigned short f2bf(float f) {
  unsigned u = __float_as_uint(f);
  return (unsigned short)((u + 0x7FFFu + ((u >> 16) & 1u)) >> 16);
}
// packed RNE f32x2 -> bf16x2 (low = lo, high = hi)
__device__ __forceinline__ unsigned pk2bf(float lo, float hi) {
  unsigned r;
  asm("v_cvt_pk_bf16_f32 %0, %1, %2" : "=v"(r) : "v"(lo), "v"(hi));
  return r;
}
__device__ __forceinline__ float bf2f(unsigned s) {
  return __uint_as_float((s & 0xFFFFu) << 16);
}
__device__ __forceinline__ float fast_tanh(float x) {
  float e = __expf(2.0f * fabsf(x));  // inf-safe: e=inf -> t=1
  float t = 1.0f - 2.0f / (e + 1.0f);
  return copysignf(t, x);
}
__device__ __forceinline__ float fast_sig(float x) {
  return 1.0f / (1.0f + __expf(-x));
}

// ---------------------------------------------------------------------------
// Prep: pack weights (bf16) into per-wave MFMA A-fragment order (unchanged
// layout from rounds 2-6; the 8-wave kernel re-indexes the same pack).
// ---------------------------------------------------------------------------
__global__ __launch_bounds__(256) void pack_w(
    const float* __restrict__ conv_w, const float* __restrict__ w1x1,
    unsigned short* __restrict__ wpackA, unsigned short* __restrict__ wpack1) {
  const int NA = NL_ * 4 * 4 * 12 * 64 * 8;  // 983040
  int idx = blockIdx.x * 256 + threadIdx.x;
  if (idx < NA) {
    int j = idx & 7;
    int t1 = idx >> 3;
    int l = t1 & 63;
    int t2 = t1 >> 6;
    int ks = t2 % 12;
    int t3 = t2 / 12;
    int f = t3 & 3;
    int t4 = t3 >> 2;
    int w = t4 & 3;
    int li = t4 >> 2;
    int o = 32 * w + 16 * (f & 1) + 128 * (f >> 1) + (l & 15);
    int ck = 32 * ks + 8 * (l >> 4) + j;
    int c = ck & 127, k = ck >> 7;
    wpackA[idx] = f2bf(conv_w[((li * TCH_ + o) * CH_ + c) * 3 + k]);
  } else {
    int i2 = idx - NA;
    if (i2 < NL_ * 4 * 2 * 4 * 64 * 8) {
      int j = i2 & 7;
      int t1 = i2 >> 3;
      int l = t1 & 63;
      int t2 = t1 >> 6;
      int ks = t2 & 3;
      int t3 = t2 >> 2;
      int p = t3 & 1;
      int t4 = t3 >> 1;
      int w = t4 & 3;
      int li = t4 >> 2;
      int o = 32 * w + 16 * p + (l & 15);
      int c = 32 * ks + 8 * (l >> 4) + j;
      wpack1[i2] = f2bf(w1x1[(li * CH_ + o) * CH_ + c]);
    }
  }
}

// ---------------------------------------------------------------------------
// Rechannel into bf16 [b][t][c]: hb[b][t][c] = bf16(w_re[c] * x[b][t])
// ---------------------------------------------------------------------------
__global__ __launch_bounds__(256) void rechannel_k(
    const float* __restrict__ x, const float* __restrict__ w_re,
    unsigned short* __restrict__ hb) {
  int flat = blockIdx.x * 256 + threadIdx.x;  // B*T*16 chunks of 8 ch
  int cid = flat & 15;
  int t = (flat >> 4) & (T_ - 1);
  int b = flat >> 18;
  float xv = x[b * T_ + t];
  const float* wr = w_re + cid * 8;
  union { short8 s; unsigned short u[8]; } o;
#pragma unroll
  for (int j = 0; j < 8; ++j) o.u[j] = f2bf(wr[j] * xv);
  *(short8*)(hb + (size_t)(b * T_ + t) * CH_ + cid * 8) = o.s;
}

// ---------------------------------------------------------------------------
// out_init: out[b][t] = b_head + sum_c w_head[c]*head_init[b][c][t]
// ---------------------------------------------------------------------------
__global__ __launch_bounds__(256) void out_init_k(
    const float* __restrict__ head_init, const float* __restrict__ w_head,
    const float* __restrict__ b_head, float* __restrict__ out) {
  int idx = blockIdx.x * 256 + threadIdx.x;  // over B*T
  int b = idx / T_;
  int t = idx - b * T_;
  float acc = b_head[0];
#pragma unroll 8
  for (int c = 0; c < CH_; ++c)
    acc += w_head[c] * head_init[(b * CH_ + c) * T_ + t];
  out[idx] = acc;
}

// ---------------------------------------------------------------------------
// One fused layer, 512 threads = 8 waves, t-tile 64, 3 blocks/CU.
// Wave w owns the o-pair (lo = 16w..16w+15, hi = lo+128) over all 64 t-cols.
// shP aliases the tap-0 slab of shH (dead after conv GEMM, barrier-protected).
// LDS: shH 50176 B + shR 2048 B = 52224 B -> 3 blocks/CU, 24 waves/CU.
// ---------------------------------------------------------------------------
__global__ __launch_bounds__(512, 6) void layer_k(
    const unsigned short* __restrict__ hin,  // bf16 [b][t][c]
    unsigned short* __restrict__ hob,        // bf16 [b][t][c] (layers 0..8)
    float* __restrict__ hof,                 // fp32 [b][c][t] (layer 9)
    const float* __restrict__ cin, float* __restrict__ out,
    const unsigned short* __restrict__ wA,   // conv A-frag pack (this layer)
    const unsigned short* __restrict__ w1p,  // 1x1 A-frag pack (this layer)
    const float* __restrict__ bconv,         // [256]
    const float* __restrict__ wmix,          // [256]
    const float* __restrict__ b1,            // [128]
    const float* __restrict__ w_head,        // [128]
    int d, int is_final) {
  __shared__ unsigned shH[TT_ * SHW_];  // [tt][k*128+c] bf16 (50176 B)
  __shared__ float shR[8 * 4 * 16];     // [wave][q][r] head partials (2 KB)

  const int tid = threadIdx.x;
  const int b = blockIdx.y;
  const int t0 = blockIdx.x * TT_;

  // ---- stage H tiles (bf16, fully coalesced 16B chunks) ----
#pragma unroll
  for (int it = 0; it < 6; ++it) {
    int flat = it * 512 + tid;
    int cid = flat & 15;           // 16B chunk within row (8 channels)
    int tt = (flat >> 4) & 63;
    int k = flat >> 10;            // 0..2
    int t = t0 + tt - (2 - k) * d;
    uint4 v = make_uint4(0u, 0u, 0u, 0u);
    if (t >= 0)
      v = *(const uint4*)(hin + ((size_t)(b * T_ + t) * CH_ + cid * 8));
    *(uint4*)(shH + tt * SHW_ + k * 64 + cid * 4) = v;
  }
  __syncthreads();

  const int wave = __builtin_amdgcn_readfirstlane(tid >> 6);  // 0..7
  const int lane = tid & 63;
  const int r = lane & 15;
  const int g = lane >> 4;
  const int wlo = (wave >> 1) * 4 + (wave & 1);  // conv pack slot (lo); hi=+2

  // ---- conv GEMM: z[256x64] = W[256x384] * H[384x64], 12 K-steps ----
  f32x4 accLo[4], accHi[4];
#pragma unroll
  for (int q = 0; q < 4; ++q) {
    accLo[q] = (f32x4){0.f, 0.f, 0.f, 0.f};
    accHi[q] = (f32x4){0.f, 0.f, 0.f, 0.f};
  }

  const short8* wAv = (const short8*)wA;
#pragma unroll
  for (int ks = 0; ks < 12; ++ks) {
    short8 bf[4];
#pragma unroll
    for (int q = 0; q < 4; ++q)
      bf[q] = *(const short8*)(shH + (16 * q + r) * SHW_ + 16 * ks + 4 * g);
    short8 alo = wAv[(wlo * 12 + ks) * 64 + lane];
    short8 ahi = wAv[((wlo + 2) * 12 + ks) * 64 + lane];
#pragma unroll
    for (int q = 0; q < 4; ++q) {
      accLo[q] = MFMA16(alo, bf[q], accLo[q]);
      accHi[q] = MFMA16(ahi, bf[q], accHi[q]);
    }
  }
  __syncthreads();  // tap-0 slab now dead everywhere -> post may overwrite it

  // ---- gating + in-register head partials; post -> tap-0 alias ----
  float bcL[4], bcH[4], wmL[4], wmH[4], whv[4];
#pragma unroll
  for (int j = 0; j < 4; ++j) {
    int o = 16 * wave + 4 * g + j;
    bcL[j] = bconv[o];
    bcH[j] = bconv[o + CH_];
    wmL[j] = wmix[o];
    wmH[j] = wmix[o + CH_];
    whv[j] = w_head[o];
  }

  float hs[4];
#pragma unroll
  for (int q = 0; q < 4; ++q) {
    float cq = cin[b * T_ + t0 + 16 * q + r];
    float pv[4];
#pragma unroll
    for (int j = 0; j < 4; ++j) {
      float zl = accLo[q][j] + bcL[j] + wmL[j] * cq;
      float zh = accHi[q][j] + bcH[j] + wmH[j] * cq;
      pv[j] = fast_tanh(zl) * fast_sig(zh);
    }
    hs[q] = whv[0] * pv[0] + whv[1] * pv[1] + whv[2] * pv[2] + whv[3] * pv[3];
    uint2 pk;
    pk.x = pk2bf(pv[0], pv[1]);
    pk.y = pk2bf(pv[2], pv[3]);
    // post[t][c], c = 16*wave + 4*g + (0..3)  (dwords 0..63 of row)
    *(uint2*)(shH + (16 * q + r) * SHW_ + 8 * wave + 2 * g) = pk;
  }
  __syncthreads();

  // ---- 1x1 GEMM: delta[128x64] = W1 * post (from tap-0 alias) ----
  f32x4 acc2[4];
#pragma unroll
  for (int q = 0; q < 4; ++q) acc2[q] = (f32x4){0.f, 0.f, 0.f, 0.f};

  const short8* w1v = (const short8*)w1p;
#pragma unroll
  for (int ks = 0; ks < 4; ++ks) {
    short8 bp[4];
#pragma unroll
    for (int q = 0; q < 4; ++q)
      bp[q] = *(const short8*)(shH + (16 * q + r) * SHW_ + 16 * ks + 4 * g);
    short8 a1 = w1v[(wave * 4 + ks) * 64 + lane];
#pragma unroll
    for (int q = 0; q < 4; ++q) acc2[q] = MFMA16(a1, bp[q], acc2[q]);
  }

  // ---- residual: res = hin(center tap, LDS dw 128..191) + b1 + delta ----
  float res[4][4];
  float b1v[4];
#pragma unroll
  for (int j = 0; j < 4; ++j) b1v[j] = b1[16 * wave + 4 * g + j];
#pragma unroll
  for (int q = 0; q < 4; ++q) {
    uint2 hv = *(const uint2*)(shH + (16 * q + r) * SHW_ + 128 + 8 * wave + 2 * g);
    res[q][0] = bf2f(hv.x) + b1v[0] + acc2[q][0];
    res[q][1] = bf2f(hv.x >> 16) + b1v[1] + acc2[q][1];
    res[q][2] = bf2f(hv.y) + b1v[2] + acc2[q][2];
    res[q][3] = bf2f(hv.y >> 16) + b1v[3] + acc2[q][3];
  }

  // ---- head partial reduce across g-groups, then waves ----
#pragma unroll
  for (int q = 0; q < 4; ++q) {
    hs[q] += __shfl_xor(hs[q], 16);
    hs[q] += __shfl_xor(hs[q], 32);
  }
  if (g == 0) {
#pragma unroll
    for (int q = 0; q < 4; ++q) shR[(wave * 4 + q) * 16 + r] = hs[q];
  }
  __syncthreads();  // shR ready; all post/center-tap reads done

  if (tid < 64) {
    int q = tid >> 4, rr = tid & 15;
    float tot = 0.f;
#pragma unroll
    for (int w = 0; w < 8; ++w) tot += shR[(w * 4 + q) * 16 + rr];
    out[b * T_ + t0 + 16 * q + rr] += tot;
  }

  if (!is_final) {
    // stage hout tile (bf16) into shH dwords 0..63, then coalesced copy
#pragma unroll
    for (int q = 0; q < 4; ++q) {
      uint2 pk;
      pk.x = pk2bf(res[q][0], res[q][1]);
      pk.y = pk2bf(res[q][2], res[q][3]);
      *(uint2*)(shH + (16 * q + r) * SHW_ + 8 * wave + 2 * g) = pk;
    }
    __syncthreads();
#pragma unroll
    for (int it = 0; it < 2; ++it) {
      int flat = it * 512 + tid;
      int cid = flat & 15;
      int tt = flat >> 4;
      *(uint4*)(hob + ((size_t)(b * T_ + t0 + tt) * CH_ + cid * 8)) =
          *(const uint4*)(shH + tt * SHW_ + cid * 4);
    }
  } else {
    // final layer: fp32 [b][c][t] into d_out
#pragma unroll
    for (int q = 0; q < 4; ++q) {
#pragma unroll
      for (int j = 0; j < 4; ++j)
        hof[(size_t)(b * CH_ + 16 * wave + 4 * g + j) * T_ + t0 + 16 * q + r] =
            res[q][j];
    }
  }
}

extern "C" void kernel_launch(void* const* d_in, const int* in_sizes, int n_in,
                              void* d_out, int out_size, void* d_ws, size_t ws_size,
                              hipStream_t stream) {
  const float* x         = (const float*)d_in[0];
  const float* c         = (const float*)d_in[1];
  const float* head_init = (const float*)d_in[2];
  const float* w_re      = (const float*)d_in[3];
  const float* conv_w    = (const float*)d_in[4];
  const float* conv_b    = (const float*)d_in[5];
  const float* mix_w     = (const float*)d_in[6];
  const float* w1x1      = (const float*)d_in[7];
  const float* b1x1      = (const float*)d_in[8];
  const float* w_head    = (const float*)d_in[9];
  const float* b_head    = (const float*)d_in[10];

  float* out = (float*)d_out;          // [B*T]
  float* hof = out + B_ * T_;          // fp32 h region of d_out

  unsigned short* hb0 = (unsigned short*)d_ws;          // bf16 h ping (16MB)
  unsigned short* hb1 = hb0 + (size_t)B_ * T_ * CH_;    // bf16 h pong (16MB)
  unsigned short* wpackA = hb1 + (size_t)B_ * T_ * CH_;
  unsigned short* wpack1 = wpackA + NL_ * 4 * 4 * 12 * 64 * 8;

  const int n_pack = NL_ * 4 * 4 * 12 * 64 * 8 + NL_ * 4 * 2 * 4 * 64 * 8;
  pack_w<<<(n_pack + 255) / 256, 256, 0, stream>>>(conv_w, w1x1, wpackA, wpack1);

  rechannel_k<<<(B_ * T_ * 16) / 256, 256, 0, stream>>>(x, w_re, hb0);
  out_init_k<<<(B_ * T_) / 256, 256, 0, stream>>>(head_init, w_head, b_head, out);

  const int dil[NL_] = {1, 2, 4, 8, 16, 32, 64, 128, 256, 512};
  for (int li = 0; li < NL_; ++li) {
    const unsigned short* hin = (li & 1) ? hb1 : hb0;
    unsigned short* hob       = (li & 1) ? hb0 : hb1;
    int is_final = (li == NL_ - 1);
    layer_k<<<dim3(T_ / TT_, B_), 512, 0, stream>>>(
        hin, hob, hof, c, out,
        wpackA + li * (4 * 4 * 12 * 64 * 8),
        wpack1 + li * (4 * 2 * 4 * 64 * 8),
        conv_b + li * TCH_,
        mix_w + li * TCH_,
        b1x1 + li * CH_,
        w_head,
        dil[li], is_final);
  }
}

// Round 9
// 310.827 us; speedup vs baseline: 2.7076x; 1.0514x over previous
//
#include <hip/hip_runtime.h>
#include <hip/hip_bf16.h>

#define B_   4
#define T_   16384
#define CH_  128
#define TCH_ 256
#define NL_  10
#define TT_  64
#define SHW_ 196          // shH row stride in dwords (384 bf16 + 8 pad)

typedef __attribute__((ext_vector_type(8))) short short8;
typedef __attribute__((ext_vector_type(16))) float f32x16;

#define MFMA32(a, b, c) __builtin_amdgcn_mfma_f32_32x32x16_bf16(a, b, c, 0, 0, 0)

__device__ __forceinline__ unsigned short f2bf(float f) {
  unsigned u = __float_as_uint(f);
  return (unsigned short)((u + 0x7FFFu + ((u >> 16) & 1u)) >> 16);
}
// packed RNE f32x2 -> bf16x2 (low = lo, high = hi)
__device__ __forceinline__ unsigned pk2bf(float lo, float hi) {
  unsigned r;
  asm("v_cvt_pk_bf16_f32 %0, %1, %2" : "=v"(r) : "v"(lo), "v"(hi));
  return r;
}
__device__ __forceinline__ float bf2f(unsigned s) {
  return __uint_as_float((s & 0xFFFFu) << 16);
}
__device__ __forceinline__ float fast_tanh(float x) {
  float e = __expf(2.0f * fabsf(x));  // inf-safe: e=inf -> t=1
  float t = 1.0f - 2.0f / (e + 1.0f);
  return copysignf(t, x);
}
__device__ __forceinline__ float fast_sig(float x) {
  return 1.0f / (1.0f + __expf(-x));
}

// ---------------------------------------------------------------------------
// Prep: pack weights (bf16) into 32x32x16 MFMA A-fragment order.
// A-frag layout (32x32x16): lane l -> m = l&31, k = 8*(l>>5) + j (j=0..7).
// conv: wpackA[li][of(8)][ks(24)][lane][j] = conv_w[o=32of+(l&31)]
//         [ck = 16ks + 8(l>>5)+j], ck = ktap*128 + c.
// 1x1:  wpack1[li][of(4)][ks(8)][lane][j] = w1x1[o=32of+(l&31)][c=16ks+8(l>>5)+j]
// ---------------------------------------------------------------------------
__global__ __launch_bounds__(256) void pack_w(
    const float* __restrict__ conv_w, const float* __restrict__ w1x1,
    unsigned short* __restrict__ wpackA, unsigned short* __restrict__ wpack1) {
  const int NA = NL_ * 8 * 24 * 64 * 8;  // 983040
  int idx = blockIdx.x * 256 + threadIdx.x;
  if (idx < NA) {
    int j = idx & 7;
    int l = (idx >> 3) & 63;
    int t2 = idx >> 9;          // ks + 24*(of + 8*li)
    int ks = t2 % 24;
    int t3 = t2 / 24;
    int of = t3 & 7;
    int li = t3 >> 3;
    int o = 32 * of + (l & 31);
    int ck = 16 * ks + 8 * (l >> 5) + j;
    int c = ck & 127, ktap = ck >> 7;
    wpackA[idx] = f2bf(conv_w[((li * TCH_ + o) * CH_ + c) * 3 + ktap]);
  } else {
    int i2 = idx - NA;
    if (i2 < NL_ * 4 * 8 * 64 * 8) {
      int j = i2 & 7;
      int l = (i2 >> 3) & 63;
      int ks = (i2 >> 9) & 7;
      int of = (i2 >> 12) & 3;
      int li = i2 >> 14;
      int o = 32 * of + (l & 31);
      int c = 16 * ks + 8 * (l >> 5) + j;
      wpack1[i2] = f2bf(w1x1[(li * CH_ + o) * CH_ + c]);
    }
  }
}

// ---------------------------------------------------------------------------
// Rechannel into bf16 [b][t][c]: hb[b][t][c] = bf16(w_re[c] * x[b][t])
// ---------------------------------------------------------------------------
__global__ __launch_bounds__(256) void rechannel_k(
    const float* __restrict__ x, const float* __restrict__ w_re,
    unsigned short* __restrict__ hb) {
  int flat = blockIdx.x * 256 + threadIdx.x;  // B*T*16 chunks of 8 ch
  int cid = flat & 15;
  int t = (flat >> 4) & (T_ - 1);
  int b = flat >> 18;
  float xv = x[b * T_ + t];
  const float* wr = w_re + cid * 8;
  union { short8 s; unsigned short u[8]; } o;
#pragma unroll
  for (int j = 0; j < 8; ++j) o.u[j] = f2bf(wr[j] * xv);
  *(short8*)(hb + (size_t)(b * T_ + t) * CH_ + cid * 8) = o.s;
}

// ---------------------------------------------------------------------------
// out_init: out[b][t] = b_head + sum_c w_head[c]*head_init[b][c][t]
// ---------------------------------------------------------------------------
__global__ __launch_bounds__(256) void out_init_k(
    const float* __restrict__ head_init, const float* __restrict__ w_head,
    const float* __restrict__ b_head, float* __restrict__ out) {
  int idx = blockIdx.x * 256 + threadIdx.x;  // over B*T
  int b = idx / T_;
  int t = idx - b * T_;
  float acc = b_head[0];
#pragma unroll 8
  for (int c = 0; c < CH_; ++c)
    acc += w_head[c] * head_init[(b * CH_ + c) * T_ + t];
  out[idx] = acc;
}

// ---------------------------------------------------------------------------
// One fused layer, 256 threads = 4 waves, t-tile 64, 32x32x16 MFMA.
// Wave w owns o-frags {w, w+4} (o-lo = 32w.., o-hi = o-lo+128) x both
// t-halves (tf=0: t rows 0..31, tf=1: 32..63).
// C/D layout: t = 32tf + (lane&31), o = 32of + (reg&3) + 8(reg>>2) + 4(lane>>5).
// shP aliases tap-0 slab of shH (dead after conv, barrier-protected).
// LDS: shH 50176 B + shR 1024 B -> 3 blocks/CU.
// ---------------------------------------------------------------------------
__global__ __launch_bounds__(256, 3) void layer_k(
    const unsigned short* __restrict__ hin,  // bf16 [b][t][c]
    unsigned short* __restrict__ hob,        // bf16 [b][t][c] (layers 0..8)
    float* __restrict__ hof,                 // fp32 [b][c][t] (layer 9)
    const float* __restrict__ cin, float* __restrict__ out,
    const unsigned short* __restrict__ wA,   // conv A-frag pack (this layer)
    const unsigned short* __restrict__ w1p,  // 1x1 A-frag pack (this layer)
    const float* __restrict__ bconv,         // [256]
    const float* __restrict__ wmix,          // [256]
    const float* __restrict__ b1,            // [128]
    const float* __restrict__ w_head,        // [128]
    int d, int is_final) {
  __shared__ unsigned shH[TT_ * SHW_];  // [tt][k*128+c] bf16 (50176 B)
  __shared__ float shR[4 * 64];         // [wave][t] head partials (1 KB)

  const int tid = threadIdx.x;
  const int b = blockIdx.y;
  // bijective XCD swizzle: 256 tiles per b, 8 XCDs, 32-tile chunks
  const int tile = (blockIdx.x & 7) * 32 + (blockIdx.x >> 3);
  const int t0 = tile * TT_;

  // ---- stage H tiles (bf16, fully coalesced 16B chunks) ----
#pragma unroll
  for (int it = 0; it < 12; ++it) {
    int flat = it * 256 + tid;
    int cid = flat & 15;           // 16B chunk within tap row (8 channels)
    int tt = (flat >> 4) & 63;
    int k = flat >> 10;            // 0..2
    int t = t0 + tt - (2 - k) * d;
    uint4 v = make_uint4(0u, 0u, 0u, 0u);
    if (t >= 0)
      v = *(const uint4*)(hin + ((size_t)(b * T_ + t) * CH_ + cid * 8));
    *(uint4*)(shH + tt * SHW_ + k * 64 + cid * 4) = v;
  }
  __syncthreads();

  const int wave = __builtin_amdgcn_readfirstlane(tid >> 6);  // 0..3
  const int lane = tid & 63;
  const int ln = lane & 31;       // -> t within half-tile (C) / m,n (A,B)
  const int kg = lane >> 5;       // k-group (A,B) / o-offset +4 (C)

  // ---- conv GEMM: z[256x64] = W[256x384] * H[384x64], 24 K-steps ----
  f32x16 aL0, aL1, aH0, aH1;
#pragma unroll
  for (int i = 0; i < 16; ++i) { aL0[i] = 0.f; aL1[i] = 0.f; aH0[i] = 0.f; aH1[i] = 0.f; }

  const short8* wAv = (const short8*)wA;
#pragma unroll
  for (int ks = 0; ks < 24; ++ks) {
    short8 b0 = *(const short8*)(shH + ln * SHW_ + 8 * ks + 4 * kg);
    short8 b1f = *(const short8*)(shH + (32 + ln) * SHW_ + 8 * ks + 4 * kg);
    short8 alo = wAv[(wave * 24 + ks) * 64 + lane];
    short8 ahi = wAv[((wave + 4) * 24 + ks) * 64 + lane];
    aL0 = MFMA32(alo, b0, aL0);
    aL1 = MFMA32(alo, b1f, aL1);
    aH0 = MFMA32(ahi, b0, aH0);
    aH1 = MFMA32(ahi, b1f, aH1);
  }
  __syncthreads();  // tap-0 slab dead everywhere -> post may overwrite it

  // ---- gating + head partials; post -> tap-0 alias (dwords 0..63) ----
  const float cq0 = cin[b * T_ + t0 + ln];
  const float cq1 = cin[b * T_ + t0 + 32 + ln];
  float hs0 = 0.f, hs1 = 0.f;
#pragma unroll
  for (int r2 = 0; r2 < 4; ++r2) {
    const int o4 = 32 * wave + 8 * r2 + 4 * kg;
    const float4 bcL = *(const float4*)(bconv + o4);
    const float4 bcH = *(const float4*)(bconv + CH_ + o4);
    const float4 wmL = *(const float4*)(wmix + o4);
    const float4 wmH = *(const float4*)(wmix + CH_ + o4);
    const float4 wh = *(const float4*)(w_head + o4);
    float pv0[4], pv1[4];
#pragma unroll
    for (int j2 = 0; j2 < 4; ++j2) {
      const float bl = ((const float*)&bcL)[j2], bh = ((const float*)&bcH)[j2];
      const float ml = ((const float*)&wmL)[j2], mh = ((const float*)&wmH)[j2];
      const float w = ((const float*)&wh)[j2];
      float zl0 = aL0[4 * r2 + j2] + bl + ml * cq0;
      float zh0 = aH0[4 * r2 + j2] + bh + mh * cq0;
      pv0[j2] = fast_tanh(zl0) * fast_sig(zh0);
      hs0 += w * pv0[j2];
      float zl1 = aL1[4 * r2 + j2] + bl + ml * cq1;
      float zh1 = aH1[4 * r2 + j2] + bh + mh * cq1;
      pv1[j2] = fast_tanh(zl1) * fast_sig(zh1);
      hs1 += w * pv1[j2];
    }
    uint2 pk;
    const int dw = 16 * wave + 4 * r2 + 2 * kg;
    pk.x = pk2bf(pv0[0], pv0[1]);
    pk.y = pk2bf(pv0[2], pv0[3]);
    *(uint2*)(shH + ln * SHW_ + dw) = pk;
    pk.x = pk2bf(pv1[0], pv1[1]);
    pk.y = pk2bf(pv1[2], pv1[3]);
    *(uint2*)(shH + (32 + ln) * SHW_ + dw) = pk;
  }
  // head partial reduce across kg halves; lanes 0..31 hold t = ln (+32 tf)
  hs0 += __shfl_xor(hs0, 32);
  hs1 += __shfl_xor(hs1, 32);
  if (lane < 32) {
    shR[wave * 64 + ln] = hs0;
    shR[wave * 64 + 32 + ln] = hs1;
  }
  __syncthreads();  // post + shR ready

  // ---- 1x1 GEMM: delta[128x64] = W1 * post (from tap-0 alias) ----
  f32x16 d0, d1;
#pragma unroll
  for (int i = 0; i < 16; ++i) { d0[i] = 0.f; d1[i] = 0.f; }

  const short8* w1v = (const short8*)w1p;
#pragma unroll
  for (int ks = 0; ks < 8; ++ks) {
    short8 p0 = *(const short8*)(shH + ln * SHW_ + 8 * ks + 4 * kg);
    short8 p1 = *(const short8*)(shH + (32 + ln) * SHW_ + 8 * ks + 4 * kg);
    short8 a = w1v[(wave * 8 + ks) * 64 + lane];
    d0 = MFMA32(a, p0, d0);
    d1 = MFMA32(a, p1, d1);
  }

  // ---- head output (reads shR, written pre-barrier) ----
  if (tid < 64) {
    float tot = shR[tid] + shR[64 + tid] + shR[128 + tid] + shR[192 + tid];
    out[b * T_ + t0 + tid] += tot;
  }

  // ---- residual: res = hin(center tap, dw 128..191) + b1 + delta ----
  float res0[16], res1[16];
#pragma unroll
  for (int r2 = 0; r2 < 4; ++r2) {
    const int o4 = 32 * wave + 8 * r2 + 4 * kg;
    const float4 b14 = *(const float4*)(b1 + o4);
    const int dw = 16 * wave + 4 * r2 + 2 * kg;
    uint2 h0 = *(const uint2*)(shH + ln * SHW_ + 128 + dw);
    uint2 h1 = *(const uint2*)(shH + (32 + ln) * SHW_ + 128 + dw);
    res0[4 * r2 + 0] = bf2f(h0.x) + ((const float*)&b14)[0] + d0[4 * r2 + 0];
    res0[4 * r2 + 1] = bf2f(h0.x >> 16) + ((const float*)&b14)[1] + d0[4 * r2 + 1];
    res0[4 * r2 + 2] = bf2f(h0.y) + ((const float*)&b14)[2] + d0[4 * r2 + 2];
    res0[4 * r2 + 3] = bf2f(h0.y >> 16) + ((const float*)&b14)[3] + d0[4 * r2 + 3];
    res1[4 * r2 + 0] = bf2f(h1.x) + ((const float*)&b14)[0] + d1[4 * r2 + 0];
    res1[4 * r2 + 1] = bf2f(h1.x >> 16) + ((const float*)&b14)[1] + d1[4 * r2 + 1];
    res1[4 * r2 + 2] = bf2f(h1.y) + ((const float*)&b14)[2] + d1[4 * r2 + 2];
    res1[4 * r2 + 3] = bf2f(h1.y >> 16) + ((const float*)&b14)[3] + d1[4 * r2 + 3];
  }

  if (!is_final) {
    __syncthreads();  // all post/ctap reads done -> reuse dwords 0..63
#pragma unroll
    for (int r2 = 0; r2 < 4; ++r2) {
      const int dw = 16 * wave + 4 * r2 + 2 * kg;
      uint2 pk;
      pk.x = pk2bf(res0[4 * r2 + 0], res0[4 * r2 + 1]);
      pk.y = pk2bf(res0[4 * r2 + 2], res0[4 * r2 + 3]);
      *(uint2*)(shH + ln * SHW_ + dw) = pk;
      pk.x = pk2bf(res1[4 * r2 + 0], res1[4 * r2 + 1]);
      pk.y = pk2bf(res1[4 * r2 + 2], res1[4 * r2 + 3]);
      *(uint2*)(shH + (32 + ln) * SHW_ + dw) = pk;
    }
    __syncthreads();
#pragma unroll
    for (int it = 0; it < 4; ++it) {
      int flat = it * 256 + tid;
      int cid = flat & 15;
      int tt = flat >> 4;
      *(uint4*)(hob + ((size_t)(b * T_ + t0 + tt) * CH_ + cid * 8)) =
          *(const uint4*)(shH + tt * SHW_ + cid * 4);
    }
  } else {
    // final layer: fp32 [b][c][t] into d_out
#pragma unroll
    for (int r2 = 0; r2 < 4; ++r2) {
#pragma unroll
      for (int j2 = 0; j2 < 4; ++j2) {
        const int o = 32 * wave + 8 * r2 + 4 * kg + j2;
        hof[(size_t)(b * CH_ + o) * T_ + t0 + ln] = res0[4 * r2 + j2];
        hof[(size_t)(b * CH_ + o) * T_ + t0 + 32 + ln] = res1[4 * r2 + j2];
      }
    }
  }
}

extern "C" void kernel_launch(void* const* d_in, const int* in_sizes, int n_in,
                              void* d_out, int out_size, void* d_ws, size_t ws_size,
                              hipStream_t stream) {
  const float* x         = (const float*)d_in[0];
  const float* c         = (const float*)d_in[1];
  const float* head_init = (const float*)d_in[2];
  const float* w_re      = (const float*)d_in[3];
  const float* conv_w    = (const float*)d_in[4];
  const float* conv_b    = (const float*)d_in[5];
  const float* mix_w     = (const float*)d_in[6];
  const float* w1x1      = (const float*)d_in[7];
  const float* b1x1      = (const float*)d_in[8];
  const float* w_head    = (const float*)d_in[9];
  const float* b_head    = (const float*)d_in[10];

  float* out = (float*)d_out;          // [B*T]
  float* hof = out + B_ * T_;          // fp32 h region of d_out

  unsigned short* hb0 = (unsigned short*)d_ws;          // bf16 h ping (16MB)
  unsigned short* hb1 = hb0 + (size_t)B_ * T_ * CH_;    // bf16 h pong (16MB)
  unsigned short* wpackA = hb1 + (size_t)B_ * T_ * CH_;
  unsigned short* wpack1 = wpackA + NL_ * 8 * 24 * 64 * 8;

  const int n_pack = NL_ * 8 * 24 * 64 * 8 + NL_ * 4 * 8 * 64 * 8;
  pack_w<<<(n_pack + 255) / 256, 256, 0, stream>>>(conv_w, w1x1, wpackA, wpack1);

  rechannel_k<<<(B_ * T_ * 16) / 256, 256, 0, stream>>>(x, w_re, hb0);
  out_init_k<<<(B_ * T_) / 256, 256, 0, stream>>>(head_init, w_head, b_head, out);

  const int dil[NL_] = {1, 2, 4, 8, 16, 32, 64, 128, 256, 512};
  for (int li = 0; li < NL_; ++li) {
    const unsigned short* hin = (li & 1) ? hb1 : hb0;
    unsigned short* hob       = (li & 1) ? hb0 : hb1;
    int is_final = (li == NL_ - 1);
    layer_k<<<dim3(T_ / TT_, B_), 256, 0, stream>>>(
        hin, hob, hof, c, out,
        wpackA + li * (8 * 24 * 64 * 8),
        wpack1 + li * (4 * 8 * 64 * 8),
        conv_b + li * TCH_,
        mix_w + li * TCH_,
        b1x1 + li * CH_,
        w_head,
        dil[li], is_final);
  }
}